// Round 5
// baseline (99.697 us; speedup 1.0000x reference)
//
#include <hip/hip_runtime.h>
#include <stdint.h>

typedef unsigned long long u64;

#define KCAND 9
#define BATCH 16
#define NPRED 30000
#define NGT   64
#define TPB   256
#define UNR   8
#define NT    15   // ceil(30000 / (256*8))
#define INITKEY 0x7F800000FFFFFFFFULL
#define FINF __uint_as_float(0x7F800000u)

// pre-pass: compact xy into [B][N] float2 (halves cache traffic, dense loads)
__global__ __launch_bounds__(256) void compact_xy(
    const float* __restrict__ pred, float2* __restrict__ xy)
{
    int e = blockIdx.x * 256 + threadIdx.x;
    if (e < BATCH * NPRED) {
        float4 p = ((const float4*)pred)[e];
        xy[e] = make_float2(p.x, p.y);
    }
}

template <int S2, bool MASK>
__device__ __forceinline__ void load_d2(const float2* __restrict__ xyb, int i0,
                                        float gcx, float gcy, float (&d2)[UNR]) {
#pragma unroll
    for (int j = 0; j < UNR; ++j) {
        const int i = i0 + j * 64;
        const bool v = !MASK || (i < NPRED);
        float2 p = xyb[(v ? i : 0) * S2];
        float dx = __fsub_rn(gcx, p.x);
        float dy = __fsub_rn(gcy, p.y);
        float d  = __fadd_rn(__fmul_rn(dx, dx), __fmul_rn(dy, dy));
        d2[j] = v ? d : FINF;
    }
}

// S2 = float2 stride per element: 1 (compact ws) or 2 (raw pred, fallback)
template <int S2>
__global__ __launch_bounds__(TPB, 4) void atss_kernel(
    const float2* __restrict__ xy,    // [B][N] xy (stride S2 float2s)
    const float*  __restrict__ pred,  // [B, N, 4] cxcywh (epilogue only)
    const float*  __restrict__ gt,    // [B, G, 4] cxcywh
    float* __restrict__ out)          // [4][B*G*K] float32
{
#pragma clang fp contract(off)
    const int tid  = threadIdx.x;
    const int lane = tid & 63;
    const int wvid = tid >> 6;

    // XCD swizzle: XCD k (blockIdx%8) serves only images {k, k+8} -> L2-resident
    const int b = (blockIdx.x & 7) + 8 * (blockIdx.x >> 9);
    const int g = (blockIdx.x >> 3) & 63;
    const int w = b * NGT + g;

    const float4 gtb = ((const float4*)gt)[w];
    const float gcx = gtb.x, gcy = gtb.y;
    const float2* xyb   = xy + (size_t)b * NPRED * S2;
    const float4* pred4 = (const float4*)pred + (size_t)b * NPRED;

    const int ibase0 = wvid * (64 * UNR) + lane;   // + t*2048 + j*64

    // ---------- Pass A: per-lane min of d^2 ----------
    float lmin = FINF;
    for (int t = 0; t < NT - 1; ++t) {
        float d2[UNR];
        load_d2<S2, false>(xyb, t * (TPB * UNR) + ibase0, gcx, gcy, d2);
#pragma unroll
        for (int j = 0; j < UNR; ++j) lmin = fminf(lmin, d2[j]);
    }
    {
        float d2[UNR];
        load_d2<S2, true>(xyb, (NT - 1) * (TPB * UNR) + ibase0, gcx, gcy, d2);
#pragma unroll
        for (int j = 0; j < UNR; ++j) lmin = fminf(lmin, d2[j]);
    }

    // ---------- bitonic sort 64 lane-minima; T = 9th smallest (lane 8) ----------
    // Conservative: <=9 lanes can hold a true top-9 element, so the 9th-smallest
    // lane-min >= true 9th-smallest distance. Filter uses <=, exact pass decides.
    {
        float x = lmin;
#pragma unroll
        for (int k = 2; k <= 64; k <<= 1) {
#pragma unroll
            for (int j = k >> 1; j >= 1; j >>= 1) {
                float o = __shfl_xor(x, j, 64);
                bool keepmin = (((lane & k) == 0) == ((lane & j) == 0));
                x = keepmin ? fminf(x, o) : fmaxf(x, o);
            }
        }
        lmin = x;
    }
    float Tf = __uint_as_float((unsigned)__builtin_amdgcn_readlane(
                                   (int)__float_as_uint(lmin), 8));

    // ---------- Pass B: exact top-9 into replicated registers ----------
    u64 t0=INITKEY,t1=INITKEY,t2=INITKEY,t3=INITKEY,t4=INITKEY,
        t5=INITKEY,t6=INITKEY,t7=INITKEY,t8=INITKEY;

#define SW(T) { bool c_ = x < (T); u64 lo_ = c_ ? x : (T); u64 hi_ = c_ ? (T) : x; (T) = lo_; x = hi_; }
#define SWAP9 SW(t0) SW(t1) SW(t2) SW(t3) SW(t4) SW(t5) SW(t6) SW(t7) SW(t8)

#define PROCESS(I0) { \
    float dmin = d2[0]; \
    _Pragma("unroll") \
    for (int j = 1; j < UNR; ++j) dmin = fminf(dmin, d2[j]); \
    if (__ballot(dmin <= Tf) != 0ULL) { \
        _Pragma("unroll") \
        for (int j = 0; j < UNR; ++j) { \
            u64 pend = __ballot(d2[j] <= Tf); \
            while (pend) { \
                const int src = __ffsll(pend) - 1; \
                pend &= pend - 1; \
                const unsigned kd = (unsigned)__builtin_amdgcn_readlane( \
                                        (int)__float_as_uint(d2[j]), src); \
                const unsigned ki = (unsigned)((I0) - lane + j * 64 + src); \
                u64 key = ((u64)kd << 32) | ki; \
                if (key < t8) { \
                    u64 x = key; SWAP9; \
                    Tf = fminf(Tf, __uint_as_float((unsigned)(t8 >> 32))); \
                    pend &= __ballot(d2[j] <= Tf); \
                } \
            } \
        } \
    } }

    for (int t = 0; t < NT - 1; ++t) {
        const int i0 = t * (TPB * UNR) + ibase0;
        float d2[UNR];
        load_d2<S2, false>(xyb, i0, gcx, gcy, d2);
        PROCESS(i0)
    }
    {
        const int i0 = (NT - 1) * (TPB * UNR) + ibase0;
        float d2[UNR];
        load_d2<S2, true>(xyb, i0, gcx, gcy, d2);
        PROCESS(i0)
    }

    // ---------- cross-wave merge through LDS ----------
    __shared__ u64 smem[4 * KCAND];
    if (lane == 0) {
        u64* s = smem + wvid * KCAND;
        s[0]=t0; s[1]=t1; s[2]=t2; s[3]=t3; s[4]=t4;
        s[5]=t5; s[6]=t6; s[7]=t7; s[8]=t8;
    }
    __syncthreads();

    if (wvid != 0) return;

    u64 cand = (lane < 4 * KCAND) ? smem[lane] : INITKEY;
    const float cd = __uint_as_float((unsigned)(cand >> 32));
    t0=INITKEY;t1=INITKEY;t2=INITKEY;t3=INITKEY;t4=INITKEY;
    t5=INITKEY;t6=INITKEY;t7=INITKEY;t8=INITKEY;
    Tf = FINF;
    {
        u64 pend = __ballot(cd < FINF);
        while (pend) {
            const int src = __ffsll(pend) - 1;
            pend &= pend - 1;
            const unsigned kd = (unsigned)__builtin_amdgcn_readlane(
                                    (int)(unsigned)(cand >> 32), src);
            const unsigned ki = (unsigned)__builtin_amdgcn_readlane(
                                    (int)(unsigned)cand, src);
            u64 key = ((u64)kd << 32) | ki;
            if (key < t8) {
                u64 x = key; SWAP9;
                Tf = fminf(Tf, __uint_as_float((unsigned)(t8 >> 32)));
                pend &= __ballot(cd <= Tf);
            }
        }
    }

    // lane k (k<9) picks the k-th smallest from the replicated sorted list
    u64 fin = t0;
    if (lane == 1) fin = t1;
    if (lane == 2) fin = t2;
    if (lane == 3) fin = t3;
    if (lane == 4) fin = t4;
    if (lane == 5) fin = t5;
    if (lane == 6) fin = t6;
    if (lane == 7) fin = t7;
    if (lane == 8) fin = t8;

    // ---------- lanes 0..8: IoU + adaptive threshold + outputs ----------
    const bool active = (lane < KCAND);
    const unsigned idx = active ? (unsigned)(fin & 0xffffffffu) : 0u;

    float4 pb = pred4[idx];

    float gx1 = gcx - 0.5f * gtb.z, gy1 = gcy - 0.5f * gtb.w;
    float gx2 = gcx + 0.5f * gtb.z, gy2 = gcy + 0.5f * gtb.w;
    float kx1 = pb.x - 0.5f * pb.z, ky1 = pb.y - 0.5f * pb.w;
    float kx2 = pb.x + 0.5f * pb.z, ky2 = pb.y + 0.5f * pb.w;

    float ltx = fmaxf(gx1, kx1), lty = fmaxf(gy1, ky1);
    float rbx = fminf(gx2, kx2), rby = fminf(gy2, ky2);
    float wvd = fmaxf(rbx - ltx, 0.0f);
    float hvd = fmaxf(rby - lty, 0.0f);
    float inter  = wvd * hvd;
    float area_a = (gx2 - gx1) * (gy2 - gy1);
    float area_b = (kx2 - kx1) * (ky2 - ky1);
    float iou = inter / ((area_a + area_b) - inter);

    float v = active ? iou : 0.0f;
    float s = v;
#pragma unroll
    for (int m = 1; m < 64; m <<= 1) s += __shfl_xor(s, m, 64);
    float mean = s / 9.0f;

    float dev = active ? (iou - mean) : 0.0f;
    float ss = dev * dev;
#pragma unroll
    for (int m = 1; m < 64; m <<= 1) ss += __shfl_xor(ss, m, 64);
    float stdv = sqrtf(ss / 8.0f);    // ddof = 1
    float thr = mean + stdv;

    bool inside = (gx1 <= pb.x) && (pb.x <= gx2) &&
                  (gy1 <= pb.y) && (pb.y <= gy2);
    bool maskk = (iou >= thr) && inside;

    if (active) {
        const size_t chunk = (size_t)BATCH * NGT * KCAND;   // 9216
        const size_t o = (size_t)w * KCAND + lane;
        out[0 * chunk + o] = maskk ? (float)idx : -1.0f;    // pred_idx
        out[1 * chunk + o] = maskk ? (float)g   : -1.0f;    // gt_idx
        out[2 * chunk + o] = maskk ? 1.0f : 0.0f;           // mask
        out[3 * chunk + o] = iou;                           // ious
    }
#undef PROCESS
#undef SWAP9
#undef SW
}

extern "C" void kernel_launch(void* const* d_in, const int* in_sizes, int n_in,
                              void* d_out, int out_size, void* d_ws, size_t ws_size,
                              hipStream_t stream) {
    const float* pred = (const float*)d_in[0];   // [16, 30000, 4] f32
    const float* gtb  = (const float*)d_in[1];   // [16, 64, 4] f32
    float* out = (float*)d_out;                  // 4 * 16*64*9 = 36864 f32

    const size_t need = (size_t)BATCH * NPRED * sizeof(float2);   // 3.84 MB
    if (ws_size >= need) {
        float2* xyc = (float2*)d_ws;
        compact_xy<<<(BATCH * NPRED + 255) / 256, 256, 0, stream>>>(pred, xyc);
        atss_kernel<1><<<BATCH * NGT, TPB, 0, stream>>>(xyc, pred, gtb, out);
    } else {
        atss_kernel<2><<<BATCH * NGT, TPB, 0, stream>>>(
            (const float2*)pred, pred, gtb, out);
    }
}